// Round 1
// baseline (45.049 us; speedup 1.0000x reference)
//
#include <hip/hip_runtime.h>

// KroneckerLoss: per-row reductions over 4 fp32 [8192,1024] arrays + scalar MSE.
// a = sum(obs1_row); c = dot(obs2_row, [1,-1,...]); h1 = sum(hyp1_row); h2 = sum(hyp2_row)
// s1 = a*h1*c, s2 = a*h2*c; t1 = (label==1 ? 1 : -1), t2 = -t1
// out = sum_rows 0.5*((s1-t1)^2 + (s2-t2)^2)

constexpr int kB = 8192;
constexpr int kD = 1024;
constexpr int kF4PerRow = kD / 4;        // 256 float4 per row
constexpr int kWavesPerBlock = 4;        // 256 threads/block
constexpr int kChunksPerLane = kF4PerRow / 64;  // 4 float4 loads per lane per array

__global__ __launch_bounds__(256) void kron_loss_kernel(
    const float* __restrict__ obs1, const float* __restrict__ obs2,
    const float* __restrict__ hyp1, const float* __restrict__ hyp2,
    const int* __restrict__ labels, float* __restrict__ out)
{
    const int wave = threadIdx.x >> 6;
    const int lane = threadIdx.x & 63;
    const int row  = blockIdx.x * kWavesPerBlock + wave;   // grid sized exactly

    const float4* o1 = reinterpret_cast<const float4*>(obs1 + (size_t)row * kD);
    const float4* o2 = reinterpret_cast<const float4*>(obs2 + (size_t)row * kD);
    const float4* h1 = reinterpret_cast<const float4*>(hyp1 + (size_t)row * kD);
    const float4* h2 = reinterpret_cast<const float4*>(hyp2 + (size_t)row * kD);

    float a = 0.f, c = 0.f, b1 = 0.f, b2 = 0.f;
    #pragma unroll
    for (int k = 0; k < kChunksPerLane; ++k) {
        const int idx = lane + 64 * k;   // coalesced: 64 lanes x 16B = 1KB/instr
        float4 v1 = o1[idx];
        float4 v2 = o2[idx];
        float4 w1 = h1[idx];
        float4 w2 = h2[idx];
        a  += (v1.x + v1.y) + (v1.z + v1.w);
        c  += (v2.x - v2.y) + (v2.z - v2.w);   // alternating +/-: flat idx 4*c+j, parity of j
        b1 += (w1.x + w1.y) + (w1.z + w1.w);
        b2 += (w2.x + w2.y) + (w2.z + w2.w);
    }

    // 64-lane butterfly reduction (wave = 64 on CDNA4)
    #pragma unroll
    for (int off = 32; off > 0; off >>= 1) {
        a  += __shfl_down(a, off);
        c  += __shfl_down(c, off);
        b1 += __shfl_down(b1, off);
        b2 += __shfl_down(b2, off);
    }

    __shared__ float partial[kWavesPerBlock];
    if (lane == 0) {
        const float t1 = (labels[row] == 1) ? 1.f : -1.f;  // t2 = -t1
        const float ac = a * c;
        const float s1 = ac * b1;
        const float s2 = ac * b2;
        const float d1 = s1 - t1;
        const float d2 = s2 + t1;
        partial[wave] = 0.5f * (d1 * d1 + d2 * d2);
    }
    __syncthreads();
    if (threadIdx.x == 0) {
        const float sum = (partial[0] + partial[1]) + (partial[2] + partial[3]);
        atomicAdd(out, sum);   // device-scope by default on CDNA
    }
}

extern "C" void kernel_launch(void* const* d_in, const int* in_sizes, int n_in,
                              void* d_out, int out_size, void* d_ws, size_t ws_size,
                              hipStream_t stream) {
    const float* obs1   = (const float*)d_in[0];
    const float* obs2   = (const float*)d_in[1];
    const float* hyp1   = (const float*)d_in[2];
    const float* hyp2   = (const float*)d_in[3];
    const int*   labels = (const int*)d_in[4];
    float* out = (float*)d_out;

    // d_out is poisoned once before timing and never re-poisoned between
    // replays -> zero it ourselves every call (graph-capture-safe async memset).
    hipMemsetAsync(out, 0, sizeof(float), stream);

    const int rows_per_block = kWavesPerBlock;
    const int grid = kB / rows_per_block;   // 2048 blocks x 256 threads
    kron_loss_kernel<<<grid, 256, 0, stream>>>(obs1, obs2, hyp1, hyp2, labels, out);
}

// Round 2
// 37.079 us; speedup vs baseline: 1.2149x; 1.2149x over previous
//
#include <hip/hip_runtime.h>

// KroneckerLoss: per-row reductions over 4 fp32 [8192,1024] arrays + scalar MSE.
// a = sum(obs1_row); c = dot(obs2_row, [1,-1,...]); h1 = sum(hyp1_row); h2 = sum(hyp2_row)
// s1 = a*h1*c, s2 = a*h2*c; t1 = (label==1 ? 1 : -1), t2 = -t1
// out = sum_rows 0.5*((s1-t1)^2 + (s2-t2)^2)
//
// R2: 4 rows/wave (64 loads in flight per wave = MLP latency hiding),
// batched 4-row shuffle reduction (ILP across the bpermute chain),
// 512 blocks -> 512 same-address atomics (was 2048).

constexpr int kB = 8192;
constexpr int kD = 1024;
constexpr int kWavesPerBlock = 4;        // 256 threads/block
constexpr int kRowsPerWave = 4;
constexpr int kRowsPerBlock = kWavesPerBlock * kRowsPerWave;  // 16
constexpr int kChunksPerLane = (kD / 4) / 64;  // 4 float4 loads per lane per array per row

__global__ __launch_bounds__(256) void kron_loss_kernel(
    const float* __restrict__ obs1, const float* __restrict__ obs2,
    const float* __restrict__ hyp1, const float* __restrict__ hyp2,
    const int* __restrict__ labels, float* __restrict__ out)
{
    const int wave = threadIdx.x >> 6;
    const int lane = threadIdx.x & 63;
    const int row0 = (blockIdx.x * kWavesPerBlock + wave) * kRowsPerWave;

    float a[kRowsPerWave], c[kRowsPerWave], b1[kRowsPerWave], b2[kRowsPerWave];

    #pragma unroll
    for (int r = 0; r < kRowsPerWave; ++r) {
        const size_t base = (size_t)(row0 + r) * kD;
        const float4* o1 = reinterpret_cast<const float4*>(obs1 + base);
        const float4* o2 = reinterpret_cast<const float4*>(obs2 + base);
        const float4* h1 = reinterpret_cast<const float4*>(hyp1 + base);
        const float4* h2 = reinterpret_cast<const float4*>(hyp2 + base);
        float ar = 0.f, cr = 0.f, b1r = 0.f, b2r = 0.f;
        #pragma unroll
        for (int k = 0; k < kChunksPerLane; ++k) {
            const int idx = lane + 64 * k;   // coalesced: 64 lanes x 16B = 1KB/instr
            float4 v1 = o1[idx];
            float4 v2 = o2[idx];
            float4 w1 = h1[idx];
            float4 w2 = h2[idx];
            ar  += (v1.x + v1.y) + (v1.z + v1.w);
            cr  += (v2.x - v2.y) + (v2.z - v2.w);  // alternating +/- by parity of flat idx
            b1r += (w1.x + w1.y) + (w1.z + w1.w);
            b2r += (w2.x + w2.y) + (w2.z + w2.w);
        }
        a[r] = ar; c[r] = cr; b1[r] = b1r; b2[r] = b2r;
    }

    // Batched 64-lane butterfly: 6 stages x 16 independent values -> chain
    // latency hidden by 16-way ILP instead of 6-deep serial per row.
    #pragma unroll
    for (int off = 32; off > 0; off >>= 1) {
        #pragma unroll
        for (int r = 0; r < kRowsPerWave; ++r) {
            a[r]  += __shfl_down(a[r],  off);
            c[r]  += __shfl_down(c[r],  off);
            b1[r] += __shfl_down(b1[r], off);
            b2[r] += __shfl_down(b2[r], off);
        }
    }

    __shared__ float partial[kWavesPerBlock];
    if (lane == 0) {
        float loss = 0.f;
        #pragma unroll
        for (int r = 0; r < kRowsPerWave; ++r) {
            const float t1 = (labels[row0 + r] == 1) ? 1.f : -1.f;  // t2 = -t1
            const float ac = a[r] * c[r];
            const float s1 = ac * b1[r];
            const float s2 = ac * b2[r];
            const float d1 = s1 - t1;
            const float d2 = s2 + t1;
            loss += 0.5f * (d1 * d1 + d2 * d2);
        }
        partial[wave] = loss;
    }
    __syncthreads();
    if (threadIdx.x == 0) {
        const float sum = (partial[0] + partial[1]) + (partial[2] + partial[3]);
        atomicAdd(out, sum);   // 512 total, device-scope
    }
}

extern "C" void kernel_launch(void* const* d_in, const int* in_sizes, int n_in,
                              void* d_out, int out_size, void* d_ws, size_t ws_size,
                              hipStream_t stream) {
    const float* obs1   = (const float*)d_in[0];
    const float* obs2   = (const float*)d_in[1];
    const float* hyp1   = (const float*)d_in[2];
    const float* hyp2   = (const float*)d_in[3];
    const int*   labels = (const int*)d_in[4];
    float* out = (float*)d_out;

    // d_out is poisoned once and never re-poisoned between replays ->
    // zero it every call (graph-capture-safe async memset).
    hipMemsetAsync(out, 0, sizeof(float), stream);

    const int grid = kB / kRowsPerBlock;   // 512 blocks x 256 threads
    kron_loss_kernel<<<grid, 256, 0, stream>>>(obs1, obs2, hyp1, hyp2, labels, out);
}